// Round 4
// baseline (470.338 us; speedup 1.0000x reference)
//
#include <hip/hip_runtime.h>
#include <hip/hip_bf16.h>

#define EPS 1e-6f

typedef float f32x4 __attribute__((ext_vector_type(4)));
typedef __bf16 bf16x8 __attribute__((ext_vector_type(8)));
typedef short short8 __attribute__((ext_vector_type(8)));

static __device__ __forceinline__ short bf16bits(float x) {
    __hip_bfloat16 h = __float2bfloat16(x);
    short s;
    __builtin_memcpy(&s, &h, 2);
    return s;
}
static __device__ __forceinline__ float bf16back(float x) {
    __hip_bfloat16 h = __float2bfloat16(x);
    return __bfloat162float(h);
}

// ---- Kernel A: softmax + P01/P23 pair products (+transposed/swizzled/split)
__global__ __launch_bounds__(256) void kA(const float* __restrict__ logits,
                                          const float* __restrict__ y_true,
                                          float* __restrict__ P01,
                                          float* __restrict__ P23,
                                          float* __restrict__ P01T,
                                          short* __restrict__ P23s_hi,
                                          short* __restrict__ P23s_lo,
                                          int* __restrict__ label) {
    __shared__ float row[64];
    int b = blockIdx.x, t = threadIdx.x;
    if (t < 64) {
        float x = logits[b * 64 + t];
        float m = x;
        for (int mk = 8; mk >= 1; mk >>= 1) m = fmaxf(m, __shfl_xor(m, mk, 16));
        float e = __expf(x - m);
        float s = e;
        for (int mk = 8; mk >= 1; mk >>= 1) s += __shfl_xor(s, mk, 16);
        row[t] = e / s;
    }
    if (t >= 128 && t < 228) {
        int y = t - 128;
        if (y_true[b * 100 + y] > 0.5f) label[b] = y;
    }
    __syncthreads();
    int hi = t >> 4, lo = t & 15;
    float v01 = row[hi] * row[16 + lo];
    float v23 = row[32 + hi] * row[48 + lo];
    P01[b * 256 + t] = v01;
    P01T[t * 1024 + b] = v01;
    P23[b * 256 + t] = v23;
    float hf = bf16back(v23);
    int ts = t ^ ((b & 7) << 3);   // XOR swizzle (matches kC LDS read)
    P23s_hi[b * 256 + ts] = bf16bits(v23);
    P23s_lo[b * 256 + ts] = bf16bits(v23 - hf);
}

// ---- Kernel S: deterministic counting sort of b by label -------------------
__global__ __launch_bounds__(1024) void kS(const int* __restrict__ label,
                                           int* __restrict__ bidx,
                                           int* __restrict__ ylab) {
    __shared__ int lab[1024];
    __shared__ int offs[101];
    int t = threadIdx.x;
    lab[t] = label[t];
    __syncthreads();
    if (t <= 100) {
        int c = 0;
        for (int b = 0; b < 1024; ++b) c += (lab[b] < t) ? 1 : 0;
        offs[t] = c;
    }
    __syncthreads();
    int my = lab[t];
    int rank = 0;
    for (int b = 0; b < t; ++b) rank += (lab[b] == my) ? 1 : 0;
    int pos = offs[my] + rank;
    bidx[pos] = t;
    ylab[pos] = my;
}

// ---- Kernel B: segmented accumulation -> pyT_hi/lo [y][65536] bf16 ---------
// 1024 threads: 4 b-groups of 256 sorted rows; LDS atomic merge.
__global__ __launch_bounds__(1024) void kB(const float* __restrict__ P01,
                                           const float* __restrict__ P23,
                                           const int* __restrict__ bidx,
                                           const int* __restrict__ ylab,
                                           short* __restrict__ pyT_hi,
                                           short* __restrict__ pyT_lo) {
    __shared__ float numy[100 * 257];
    __shared__ float aA[1024];
    __shared__ int blist[1024];
    __shared__ unsigned char yl[1024];
    __shared__ float numjl[4][256];
    int t = threadIdx.x;
    int u = blockIdx.x;

    {
        int b = bidx[t];
        blist[t] = b;
        aA[t] = P01[b * 256 + u];
        yl[t] = (unsigned char)ylab[t];
    }
    for (int i = t; i < 100 * 257; i += 1024) numy[i] = 0.f;
    __syncthreads();

    int g = t >> 8;       // group 0..3
    int tc = t & 255;     // t-column
    int i0 = g << 8;

    float numj = 0.f, acc = 0.f;
    int ycur = yl[i0];
    float v[8];
    #pragma unroll
    for (int k = 0; k < 8; ++k) v[k] = P23[blist[i0 + k] * 256 + tc];

    for (int c = 0; c < 32; ++c) {
        float w[8];
        if (c < 31) {
            #pragma unroll
            for (int k = 0; k < 8; ++k) w[k] = P23[blist[i0 + (c + 1) * 8 + k] * 256 + tc];
        }
        #pragma unroll
        for (int k = 0; k < 8; ++k) {
            int i = i0 + c * 8 + k;
            int y = yl[i];
            if (y != ycur) {
                atomicAdd(&numy[ycur * 257 + tc], acc);
                numj += acc;
                acc = 0.f;
                ycur = y;
            }
            acc = fmaf(aA[i], v[k], acc);
        }
        if (c < 31) {
            #pragma unroll
            for (int k = 0; k < 8; ++k) v[k] = w[k];
        }
    }
    atomicAdd(&numy[ycur * 257 + tc], acc);
    numj += acc;
    numjl[g][tc] = numj;
    __syncthreads();

    // write pyT hi/lo: [y][u*256 + t], packed 2 t's per u32 store
    for (int it = 0; it < 16; ++it) {
        int idx = it * 1024 + t;      // 0..16383
        int y = idx >> 7;             // 0..127
        int t0 = (idx & 127) << 1;
        float v0 = 0.f, v1 = 0.f;
        if (y < 100) {
            float nj0 = fmaxf(numjl[0][t0] + numjl[1][t0] + numjl[2][t0] + numjl[3][t0], EPS);
            float nj1 = fmaxf(numjl[0][t0 + 1] + numjl[1][t0 + 1] + numjl[2][t0 + 1] + numjl[3][t0 + 1], EPS);
            v0 = fminf(fmaxf(numy[y * 257 + t0], EPS) / nj0, 1.0f);
            v1 = fminf(fmaxf(numy[y * 257 + t0 + 1], EPS) / nj1, 1.0f);
        }
        unsigned h0 = (unsigned short)bf16bits(v0);
        unsigned h1 = (unsigned short)bf16bits(v1);
        unsigned l0 = (unsigned short)bf16bits(v0 - bf16back(v0));
        unsigned l1 = (unsigned short)bf16bits(v1 - bf16back(v1));
        size_t ei = ((size_t)y * 65536 + (size_t)u * 256 + t0) >> 1;
        ((unsigned*)pyT_hi)[ei] = h0 | (h1 << 16);
        ((unsigned*)pyT_lo)[ei] = l0 | (l1 << 16);
    }
}

// ---- Kernel C: MFMA GEMM.  part[uspl][y][b] += P01[b,u]*(py_u x P23^T) -----
// block tile: 64b x 128y x 8u; grid = 16 bb x 32 uspl = 512 blocks (2/CU).
// 512 thr = 8 waves (2 wb x 4 wy), wave tile 32b x 32y (m=2, n=2).
// A (P23 hi/lo bf16, swizzled) in LDS (66 KB); B (pyT) streamed, 2-deep
// prefetch via 3-buffer rotation.
__global__ __launch_bounds__(512, 4) void kC(const short* __restrict__ P23s_hi,
                                             const short* __restrict__ P23s_lo,
                                             const float* __restrict__ P01T,
                                             const short* __restrict__ pyT_hi,
                                             const short* __restrict__ pyT_lo,
                                             float* __restrict__ part) {
    __shared__ short Ahi[64 * 256];
    __shared__ short Alo[64 * 256];
    __shared__ float p01s[8 * 64];
    int t = threadIdx.x;
    int bb = blockIdx.x >> 5, uspl = blockIdx.x & 31;
    int bbase = bb << 6;
    int u0 = uspl << 3;

    #pragma unroll
    for (int r = 0; r < 4; ++r) {
        int c = r * 512 + t;   // short8 chunk 0..2047
        *(short8*)(Ahi + c * 8) = *(const short8*)(P23s_hi + bbase * 256 + c * 8);
        *(short8*)(Alo + c * 8) = *(const short8*)(P23s_lo + bbase * 256 + c * 8);
    }
    p01s[t & 511] = P01T[(u0 + ((t & 511) >> 6)) * 1024 + bbase + (t & 63)];
    __syncthreads();

    int lane = t & 63;
    int wave = t >> 6;
    int wb = wave >> 2, wy = wave & 3;
    int l15 = lane & 15, l4 = lane >> 4;
    int hi8 = l4 << 3;

    int rowA0 = wb * 32 + l15;
    int swz = (rowA0 & 7) << 3;            // same for rowA0+16
    const short* pA0h = Ahi + rowA0 * 256;
    const short* pA0l = Alo + rowA0 * 256;
    const short* pA1h = pA0h + 16 * 256;
    const short* pA1l = pA0l + 16 * 256;

    const short* bh[2];
    const short* bl[2];
    #pragma unroll
    for (int n = 0; n < 2; ++n) {
        int y = wy * 32 + n * 16 + l15;
        bh[n] = pyT_hi + (size_t)y * 65536 + hi8;
        bl[n] = pyT_lo + (size_t)y * 65536 + hi8;
    }

    const f32x4 zero4 = {0.f, 0.f, 0.f, 0.f};
    f32x4 P[2][2];
    #pragma unroll
    for (int m = 0; m < 2; ++m)
        #pragma unroll
        for (int n = 0; n < 2; ++n) P[m][n] = zero4;

    bf16x8 Bh[3][2], Bl[3][2];

#define LOADB(BUF, S)                                                        \
    {                                                                        \
        int off_ = (u0 + ((S) >> 3)) * 256 + ((S) & 7) * 32;                 \
        _Pragma("unroll")                                                    \
        for (int n = 0; n < 2; ++n) {                                        \
            Bh[BUF][n] = *(const bf16x8*)(bh[n] + off_);                     \
            Bl[BUF][n] = *(const bf16x8*)(bl[n] + off_);                     \
        }                                                                    \
    }

    LOADB(0, 0)
    LOADB(1, 1)

    f32x4 Q[2][2];
    #pragma unroll
    for (int s = 0; s < 64; ++s) {
        int bufc = s % 3;
        if (s < 62) {
            LOADB((s + 2) % 3, s + 2)
        }
        int ks = s & 7;
        int aoff = (ks * 32 + hi8) ^ swz;
        bf16x8 a0h = *(const bf16x8*)(pA0h + aoff);
        bf16x8 a0l = *(const bf16x8*)(pA0l + aoff);
        bf16x8 a1h = *(const bf16x8*)(pA1h + aoff);
        bf16x8 a1l = *(const bf16x8*)(pA1l + aoff);
        #pragma unroll
        for (int n = 0; n < 2; ++n) {
            f32x4 c0 = (ks == 0) ? zero4 : Q[0][n];
            f32x4 c1 = (ks == 0) ? zero4 : Q[1][n];
            c0 = __builtin_amdgcn_mfma_f32_16x16x32_bf16(a0h, Bh[bufc][n], c0, 0, 0, 0);
            c1 = __builtin_amdgcn_mfma_f32_16x16x32_bf16(a1h, Bh[bufc][n], c1, 0, 0, 0);
            c0 = __builtin_amdgcn_mfma_f32_16x16x32_bf16(a0h, Bl[bufc][n], c0, 0, 0, 0);
            c1 = __builtin_amdgcn_mfma_f32_16x16x32_bf16(a1h, Bl[bufc][n], c1, 0, 0, 0);
            c0 = __builtin_amdgcn_mfma_f32_16x16x32_bf16(a0l, Bh[bufc][n], c0, 0, 0, 0);
            c1 = __builtin_amdgcn_mfma_f32_16x16x32_bf16(a1l, Bh[bufc][n], c1, 0, 0, 0);
            Q[0][n] = c0;
            Q[1][n] = c1;
        }
        if (ks == 7) {
            int uu = s >> 3;
            #pragma unroll
            for (int m = 0; m < 2; ++m) {
                f32x4 pv = *(const f32x4*)(p01s + uu * 64 + wb * 32 + m * 16 + (l4 << 2));
                #pragma unroll
                for (int n = 0; n < 2; ++n) P[m][n] += pv * Q[m][n];
            }
        }
    }
#undef LOADB

    size_t pbase = (size_t)uspl * 128 * 1024;
    #pragma unroll
    for (int m = 0; m < 2; ++m)
        #pragma unroll
        for (int n = 0; n < 2; ++n) {
            int y = wy * 32 + n * 16 + l15;
            int bg = bbase + wb * 32 + m * 16 + (l4 << 2);
            *(f32x4*)(part + pbase + (size_t)y * 1024 + bg) = P[m][n];
        }
}

// ---- Kernel D: reduce 32 u-split partials -> out[b*100+y] ------------------
__global__ __launch_bounds__(256) void kD(const float* __restrict__ part,
                                          float* __restrict__ out) {
    int t = threadIdx.x;
    int y = blockIdx.x >> 2;
    int b = ((blockIdx.x & 3) << 8) + t;
    float s = 0.f;
    for (int q = 0; q < 32; ++q)
        s += part[(((size_t)q * 128 + y) << 10) + b];
    out[(size_t)b * 100 + y] = s;
}

extern "C" void kernel_launch(void* const* d_in, const int* in_sizes, int n_in,
                              void* d_out, int out_size, void* d_ws, size_t ws_size,
                              hipStream_t stream) {
    const float* logits = (const float*)d_in[0];
    const float* y_true = (const float*)d_in[1];
    float* out = (float*)d_out;

    char* ws = (char*)d_ws;
    float* P01    = (float*)(ws);                        // 1 MB
    float* P23    = (float*)(ws + (1u << 20));           // 1 MB
    float* P01T   = (float*)(ws + (2u << 20));           // 1 MB
    short* P23s_hi = (short*)(ws + (3u << 20));          // 512 KB
    short* P23s_lo = (short*)(ws + (3u << 20) + (512u << 10)); // 512 KB
    int*   lab    = (int*)(ws + (4u << 20));             // 4 KB
    int*   bidx   = (int*)(ws + (4u << 20) + 4096);
    int*   ylab   = (int*)(ws + (4u << 20) + 8192);
    short* pyT_hi = (short*)(ws + (8u << 20));           // 16 MB
    short* pyT_lo = (short*)(ws + (24u << 20));          // 16 MB
    float* part   = (float*)(ws + (40u << 20));          // 16 MB

    kA<<<1024, 256, 0, stream>>>(logits, y_true, P01, P23, P01T, P23s_hi, P23s_lo, lab);
    kS<<<1, 1024, 0, stream>>>(lab, bidx, ylab);
    kB<<<256, 1024, 0, stream>>>(P01, P23, bidx, ylab, pyT_hi, pyT_lo);
    kC<<<512, 512, 0, stream>>>(P23s_hi, P23s_lo, P01T, pyT_hi, pyT_lo, part);
    kD<<<400, 256, 0, stream>>>(part, out);
}